// Round 15
// baseline (79.770 us; speedup 1.0000x reference)
//
#include <hip/hip_runtime.h>
#include <cfloat>
#include <cstdint>

// ROUND 15 = ROUND 13 CODE EXACTLY, with k_tile launched 3x for in-band
// attribution: k_tile is idempotent, so the graph stays deterministic and
// total_dur - 41.15us = 2*(k_tile + gap). No other changes.

// Problem constants (SHAPE=(96,128,128), B=2, C=32, two maxpool(K3,S2,P1) layers)
// Composed pooling: window 7, stride 4, pad 3. Output grid 2 x 24 x 32 x 32 x 32.
#define B_    2
#define OD    24
#define OH    32
#define OW    32
#define NC    32
#define NBINS (B_ * OD * OH * OW)   // 49152
#define RSTRIDE 16                  // record slots per bin
#define OVF_CAP 100000

// tile geometry: 4 x 4 x 4 output cells per workgroup
#define TZ 4
#define TY 4
#define TX 4
#define TCELLS 64
#define NTZ (OD/TZ)                 // 6
#define NTY (OH/TY)                 // 8
#define NTX (OW/TX)                 // 8
#define NTILES (B_*NTZ*NTY*NTX)     // 768 = 3 blocks/CU * 256 CU exactly
#define NBZ (TZ+1)
#define NBY (TY+1)
#define NBX (TX+1)
#define NB  (NBZ*NBY*NBX)           // 125
#define LIST_CAP 1792               // avg entries/tile ~437

// ---------------- monotone float<->uint transform ----------------
__device__ __forceinline__ unsigned xform(float f) {
    unsigned u = __float_as_uint(f);
    return u ^ ((unsigned)((int)u >> 31) | 0x80000000u);
}
__device__ __forceinline__ float unxform(unsigned t) {
    return (t == 0u) ? 0.0f
           : __uint_as_float((t >> 31) ? (t ^ 0x80000000u) : ~t);
}

// rare slow path: apply one record directly to the LDS accumulator
__device__ __forceinline__ void slow_apply(unsigned* sm_out, const float* feat,
                                           int rec, int fm, int cb) {
    unsigned idx = ((unsigned)rec) >> 8;
    for (int c2 = 0; c2 < NC; ++c2) {
        unsigned tvv = xform(feat[idx * NC + c2]);
#pragma unroll
        for (int k = 0; k < 8; ++k) {
            const int koff = ((k & 1) * (TY * TX) + ((k >> 1) & 1) * TX
                           + ((k >> 2) & 1)) * NC;
            if ((fm >> k) & 1) atomicMax(&sm_out[cb * NC + koff + c2], tvv);
        }
    }
}

// ---------------- kernels ----------------

__global__ __launch_bounds__(256) void k_zero(int* __restrict__ counts,
                                              int* __restrict__ ovf_n) {
    int i = blockIdx.x * blockDim.x + threadIdx.x;
    if (i < NBINS) counts[i] = 0;
    if (i == 0) *ovf_n = 0;
}

__global__ __launch_bounds__(256) void k_bin(const int* __restrict__ coors,
                                             int* __restrict__ counts,
                                             int* __restrict__ records,
                                             int* __restrict__ ovf_n,
                                             int2* __restrict__ ovf, int N) {
    int i = blockIdx.x * blockDim.x + threadIdx.x;
    if (i >= N) return;
    int4 cc = reinterpret_cast<const int4*>(coors)[i];   // b, z, y, x
    int bin = (((cc.x * OD + (cc.y >> 2)) * OH + (cc.z >> 2)) * OW + (cc.w >> 2));
    // bit k (k = lz + 2*ly + 4*lx): point qualifies for cell bin+(lz,ly,lx)
    int mask = 0xFF;
    if (!(cc.y & 3)) mask &= 0x55;
    if (!(cc.z & 3)) mask &= 0x33;
    if (!(cc.w & 3)) mask &= 0x0F;
    int rec = (i << 8) | mask;   // mask bit0 always set -> rec != 0
    int pos = atomicAdd(&counts[bin], 1);
    if (pos < RSTRIDE) {
        records[bin * RSTRIDE + pos] = rec;
    } else {
        int o = atomicAdd(ovf_n, 1);
        if (o < OVF_CAP) ovf[o] = make_int2(bin, rec);
    }
}

// round-10/13 tile body (best measured variant)
__global__ __launch_bounds__(512) void k_tile(const float* __restrict__ feat,
                                              const int* __restrict__ counts,
                                              const int* __restrict__ records,
                                              const int* __restrict__ ovf_n,
                                              const int2* __restrict__ ovf,
                                              float4* __restrict__ out4) {
    __shared__ unsigned sm_out[TCELLS * NC];   // 8 KB
    __shared__ int2 list[LIST_CAP];            // 14 KB
    __shared__ int sm_cursor;

    // XCD-aware swizzle (768 % 8 == 0 -> bijective)
    const int t   = (blockIdx.x & 7) * (NTILES / 8) + (blockIdx.x >> 3);
    const int tid = threadIdx.x;
    const int tx_ = t & (NTX - 1);
    const int ty_ = (t >> 3) & (NTY - 1);
    const int rest = t >> 6;                   // b*NTZ + tz, 0..11
    const int b   = (rest >= NTZ) ? 1 : 0;
    const int tz_ = rest - b * NTZ;
    const int tz0 = tz_ * TZ, ty0 = ty_ * TY, tx0 = tx_ * TX;

    if (tid == 0) sm_cursor = 0;
    for (int v = tid; v < TCELLS * NC; v += 512) sm_out[v] = 0u;
    __syncthreads();

    // ---- build compact entry list: FOUR threads per neighborhood bin ----
    if (tid < 4 * NB) {                        // 500 threads
        int bn  = tid >> 2;                    // bin 0..124
        int sl  = tid & 3;                     // record quad 0..3
        int rz  = bn / (NBY * NBX);
        int rem = bn - rz * (NBY * NBX);
        int ry  = rem / NBX;
        int rx  = rem - ry * NBX;
        int bz = tz0 - 1 + rz, by = ty0 - 1 + ry, bx = tx0 - 1 + rx;
        if ((bz | by | bx) >= 0) {             // upper side in-grid by tiling
            int bin = ((b * OD + bz) * OH + by) * OW + bx;
            int cnt = counts[bin]; if (cnt > RSTRIDE) cnt = RSTRIDE;
            int4 q = *(const int4*)(records + bin * RSTRIDE + sl * 4);
            int bi = rz - 1, bj = ry - 1, bl = rx - 1;
            int vm = 0xFF;                     // tile-validity mask per k
            if (bi < 0) vm &= 0xAA;  if (bi > TZ - 2) vm &= 0x55;
            if (bj < 0) vm &= 0xCC;  if (bj > TY - 2) vm &= 0x33;
            if (bl < 0) vm &= 0xF0;  if (bl > TX - 2) vm &= 0x0F;
            int cb = bi * (TY * TX) + bj * TX + bl;
            int rs0 = sl << 2;
            int f0 = (rs0 + 0 < cnt) ? (q.x & vm & 0xFF) : 0;
            int f1 = (rs0 + 1 < cnt) ? (q.y & vm & 0xFF) : 0;
            int f2 = (rs0 + 2 < cnt) ? (q.z & vm & 0xFF) : 0;
            int f3 = (rs0 + 3 < cnt) ? (q.w & vm & 0xFF) : 0;
            int nk = (f0 != 0) + (f1 != 0) + (f2 != 0) + (f3 != 0);
            if (nk) {
                int pos = atomicAdd(&sm_cursor, nk);
                if (f0) { if (pos < LIST_CAP) list[pos] = make_int2((q.x & ~0xFF) | f0, cb);
                          else slow_apply(sm_out, feat, q.x, f0, cb); ++pos; }
                if (f1) { if (pos < LIST_CAP) list[pos] = make_int2((q.y & ~0xFF) | f1, cb);
                          else slow_apply(sm_out, feat, q.y, f1, cb); ++pos; }
                if (f2) { if (pos < LIST_CAP) list[pos] = make_int2((q.z & ~0xFF) | f2, cb);
                          else slow_apply(sm_out, feat, q.z, f2, cb); ++pos; }
                if (f3) { if (pos < LIST_CAP) list[pos] = make_int2((q.w & ~0xFF) | f3, cb);
                          else slow_apply(sm_out, feat, q.w, f3, cb); ++pos; }
            }
        }
    }

    // ---- global overflow net (expected empty) ----
    int on = *ovf_n;
    if (on > 0 && tid == 0) {
        if (on > OVF_CAP) on = OVF_CAP;
        for (int e = 0; e < on; ++e) {
            int2 ov = ovf[e];
            int bx = ov.x & (OW - 1);
            int by = (ov.x >> 5) & (OH - 1);
            int rest2 = ov.x >> 10;            // b*OD + bz
            int bb = (rest2 >= OD) ? 1 : 0;
            int bz = rest2 - bb * OD;
            if (bb != b) continue;
            int rz = bz - (tz0 - 1), ry = by - (ty0 - 1), rx = bx - (tx0 - 1);
            if (rz < 0 || rz >= NBZ || ry < 0 || ry >= NBY || rx < 0 || rx >= NBX) continue;
            int bi = rz - 1, bj = ry - 1, bl = rx - 1;
            int vm = 0xFF;
            if (bi < 0) vm &= 0xAA;  if (bi > TZ - 2) vm &= 0x55;
            if (bj < 0) vm &= 0xCC;  if (bj > TY - 2) vm &= 0x33;
            if (bl < 0) vm &= 0xF0;  if (bl > TX - 2) vm &= 0x0F;
            int fm = ov.y & vm & 0xFF;
            if (fm) {
                int pos = atomicAdd(&sm_cursor, 1);
                if (pos < LIST_CAP)
                    list[pos] = make_int2((ov.y & ~0xFF) | fm,
                                          bi * (TY * TX) + bj * TX + bl);
            }
        }
    }
    __syncthreads();
    int total = sm_cursor; if (total > LIST_CAP) total = LIST_CAP;

    // ---- main loop: 16 slots x 8-deep ILP = 128 entries per round ----
    const int s = tid >> 5;
    const int c = tid & 31;

    for (int j0 = s; j0 < total; j0 += 128) {
        int2 e[8];
        unsigned tv[8];
#pragma unroll
        for (int u = 0; u < 8; ++u) {
            int j = j0 + 16 * u;
            e[u] = (j < total) ? list[j] : make_int2(0, 0);   // fm=0 -> no-op
        }
#pragma unroll
        for (int u = 0; u < 8; ++u)
            tv[u] = xform(feat[(((unsigned)e[u].x) >> 8) * NC + c]);
#pragma unroll
        for (int u = 0; u < 8; ++u) {
#pragma unroll
            for (int k = 0; k < 8; ++k) {
                const int koff = ((k & 1) * (TY * TX) + ((k >> 1) & 1) * TX
                               + ((k >> 2) & 1)) * NC + c;
                if ((e[u].x >> k) & 1) atomicMax(&sm_out[e[u].y * NC + koff], tv[u]);
            }
        }
    }
    __syncthreads();

    // ---- epilogue: 64 cells x 8 float4 = 512 stores, one per thread ----
    {
        const int cell = tid >> 3, quad = tid & 7;
        const int i = cell >> 4, jj = (cell >> 2) & 3, l = cell & 3;
        uint4 uv = *(const uint4*)&sm_out[cell * NC + quad * 4];
        float4 o;
        o.x = unxform(uv.x); o.y = unxform(uv.y);
        o.z = unxform(uv.z); o.w = unxform(uv.w);
        out4[(((size_t)(b * OD + tz0 + i) * OH + (ty0 + jj)) * OW
              + (tx0 + l)) * (NC / 4) + quad] = o;
    }
}

// ---------------- launch ----------------

extern "C" void kernel_launch(void* const* d_in, const int* in_sizes, int n_in,
                              void* d_out, int out_size, void* d_ws, size_t ws_size,
                              hipStream_t stream) {
    const float* feat  = (const float*)d_in[0];
    const int*   coors = (const int*)d_in[1];
    const int N = in_sizes[0] / NC;          // 200000
    float4* out4 = (float4*)d_out;           // 1572864 floats

    int*  counts  = (int*)d_ws;                     // NBINS
    int*  ovf_n   = counts + NBINS;                 // 1 (+7 pad)
    int*  records = counts + NBINS + 8;             // NBINS*16
    int2* ovf     = (int2*)(records + (size_t)NBINS * RSTRIDE);

    k_zero<<<(NBINS + 255) / 256, 256, 0, stream>>>(counts, ovf_n);
    k_bin <<<(N + 255) / 256, 256, 0, stream>>>(coors, counts, records,
                                                ovf_n, ovf, N);
    // k_tile is idempotent: 3 identical launches give identical output.
    // total - 41.15us (round-13 baseline, identical code) = 2*(k_tile + gap).
    k_tile<<<NTILES, 512, 0, stream>>>(feat, counts, records,
                                       ovf_n, (const int2*)ovf, out4);
    k_tile<<<NTILES, 512, 0, stream>>>(feat, counts, records,
                                       ovf_n, (const int2*)ovf, out4);
    k_tile<<<NTILES, 512, 0, stream>>>(feat, counts, records,
                                       ovf_n, (const int2*)ovf, out4);
}

// Round 16
// 58.832 us; speedup vs baseline: 1.3559x; 1.3559x over previous
//
#include <hip/hip_runtime.h>
#include <cfloat>
#include <cstdint>

// Problem constants (SHAPE=(96,128,128), B=2, C=32, two maxpool(K3,S2,P1) layers)
// Composed pooling: window 7, stride 4, pad 3. Output grid 2 x 24 x 32 x 32 x 32.
#define B_    2
#define OD    24
#define OH    32
#define OW    32
#define NC    32
#define NBINS (B_ * OD * OH * OW)   // 49152
#define RSTRIDE 16                  // record slots per bin
#define OVF_CAP 100000

// tile geometry: 4 x 4 x 4 output cells per workgroup
#define TZ 4
#define TY 4
#define TX 4
#define TCELLS 64
#define NTZ (OD/TZ)                 // 6
#define NTY (OH/TY)                 // 8
#define NTX (OW/TX)                 // 8
#define NTILES (B_*NTZ*NTY*NTX)     // 768 = 3 blocks/CU * 256 CU
#define NB  125                     // 5x5x5 neighborhood bins per tile

// ---------------- monotone float<->uint transform ----------------
__device__ __forceinline__ unsigned xform(float f) {
    unsigned u = __float_as_uint(f);
    return u ^ ((unsigned)((int)u >> 31) | 0x80000000u);
}
__device__ __forceinline__ float unxform(unsigned t) {
    return (t == 0u) ? 0.0f
           : __uint_as_float((t >> 31) ? (t ^ 0x80000000u) : ~t);
}

// rare path: apply one record directly to the LDS accumulator (ovf net)
__device__ __forceinline__ void slow_apply(unsigned* sm_out, const float* feat,
                                           int rec, int fm, int cb) {
    unsigned idx = ((unsigned)rec) >> 8;
    for (int c2 = 0; c2 < NC; ++c2) {
        unsigned tvv = xform(feat[idx * NC + c2]);
#pragma unroll
        for (int k = 0; k < 8; ++k) {
            const int koff = ((k & 1) * (TY * TX) + ((k >> 1) & 1) * TX
                           + ((k >> 2) & 1)) * NC;
            if ((fm >> k) & 1) atomicMax(&sm_out[cb * NC + koff + c2], tvv);
        }
    }
}

// ---------------- kernels ----------------

__global__ __launch_bounds__(256) void k_zero(int* __restrict__ counts,
                                              int* __restrict__ ovf_n) {
    int i = blockIdx.x * blockDim.x + threadIdx.x;
    if (i < NBINS) counts[i] = 0;
    if (i == 0) *ovf_n = 0;
}

__global__ __launch_bounds__(256) void k_bin(const int* __restrict__ coors,
                                             int* __restrict__ counts,
                                             int* __restrict__ records,
                                             int* __restrict__ ovf_n,
                                             int2* __restrict__ ovf, int N) {
    int i = blockIdx.x * blockDim.x + threadIdx.x;
    if (i >= N) return;
    int4 cc = reinterpret_cast<const int4*>(coors)[i];   // b, z, y, x
    int bin = (((cc.x * OD + (cc.y >> 2)) * OH + (cc.z >> 2)) * OW + (cc.w >> 2));
    // bit k (k = lz + 2*ly + 4*lx): point qualifies for cell bin+(lz,ly,lx)
    int mask = 0xFF;
    if (!(cc.y & 3)) mask &= 0x55;
    if (!(cc.z & 3)) mask &= 0x33;
    if (!(cc.w & 3)) mask &= 0x0F;
    int rec = (i << 8) | mask;   // mask bit0 always set -> rec != 0
    int pos = atomicAdd(&counts[bin], 1);
    if (pos < RSTRIDE) {
        records[bin * RSTRIDE + pos] = rec;
    } else {
        int o = atomicAdd(ovf_n, 1);
        if (o < OVF_CAP) ovf[o] = make_int2(bin, rec);
    }
}

// Fused scan+apply tile kernel: thread = (bin-slot s = tid>>5, channel ch = tid&31).
// Per neighborhood bin: read records, ONE feat load per record (32-ch coalesced),
// max-reduce into 8 per-offset registers, then ONE LDS atomicMax per present
// offset. ~4x fewer LDS pipe ops than the list-build structure (r13).
__global__ __launch_bounds__(512) void k_tile(const float* __restrict__ feat,
                                              const int* __restrict__ counts,
                                              const int* __restrict__ records,
                                              const int* __restrict__ ovf_n,
                                              const int2* __restrict__ ovf,
                                              float4* __restrict__ out4) {
    __shared__ unsigned sm_out[TCELLS * NC];   // 8 KB only

    // XCD-aware swizzle (768 % 8 == 0 -> bijective)
    const int t   = (blockIdx.x & 7) * (NTILES / 8) + (blockIdx.x >> 3);
    const int tid = threadIdx.x;
    const int tx_ = t & (NTX - 1);
    const int ty_ = (t >> 3) & (NTY - 1);
    const int rest = t >> 6;                   // b*NTZ + tz, 0..11
    const int b   = (rest >= NTZ) ? 1 : 0;
    const int tz_ = rest - b * NTZ;
    const int tz0 = tz_ * TZ, ty0 = ty_ * TY, tx0 = tx_ * TX;

    for (int v = tid; v < TCELLS * NC; v += 512) sm_out[v] = 0u;
    __syncthreads();

    const int s  = tid >> 5;
    const int ch = tid & 31;

#define PROC(R, RS) do {                                                     \
    if ((RS) < cnt) {                                                        \
        int fm = (R) & vm & 0xFF;                                            \
        if (fm) {                                                            \
            float f = feat[(((unsigned)(R)) >> 8) * NC + ch];                \
            kb |= fm;                                                        \
            _Pragma("unroll")                                                \
            for (int k = 0; k < 8; ++k)                                      \
                if ((fm >> k) & 1) m[k] = fmaxf(m[k], f);                    \
        }                                                                    \
    } } while (0)

    for (int pass = 0; pass < 8; ++pass) {
        int bn = pass * 16 + s;                // neighborhood bin 0..124
        if (bn >= NB) break;
        int rz  = bn / 25;
        int rem = bn - rz * 25;
        int ry  = rem / 5;
        int rx  = rem - ry * 5;
        int bz = tz0 - 1 + rz, by = ty0 - 1 + ry, bx = tx0 - 1 + rx;
        if ((bz | by | bx) < 0) continue;      // upper side in-grid by tiling
        int bin = ((b * OD + bz) * OH + by) * OW + bx;
        int cnt = counts[bin]; if (cnt > RSTRIDE) cnt = RSTRIDE;
        if (cnt == 0) continue;
        int bi = rz - 1, bj = ry - 1, bl = rx - 1;
        int vm = 0xFF;                         // tile-validity mask per k
        if (bi < 0) vm &= 0xAA;  if (bi > TZ - 2) vm &= 0x55;
        if (bj < 0) vm &= 0xCC;  if (bj > TY - 2) vm &= 0x33;
        if (bl < 0) vm &= 0xF0;  if (bl > TX - 2) vm &= 0x0F;
        if (!vm) continue;
        int cb = bi * (TY * TX) + bj * TX + bl;

        float m[8];
#pragma unroll
        for (int k = 0; k < 8; ++k) m[k] = -FLT_MAX;
        int kb = 0;
        const int4* rp = (const int4*)(records + bin * RSTRIDE);
#pragma unroll
        for (int g = 0; g < 4; ++g) {
            if (g * 4 >= cnt) break;
            int4 q = rp[g];
            PROC(q.x, g * 4 + 0);
            PROC(q.y, g * 4 + 1);
            PROC(q.z, g * 4 + 2);
            PROC(q.w, g * 4 + 3);
        }
        if (kb) {
#pragma unroll
            for (int k = 0; k < 8; ++k) {
                if ((kb >> k) & 1) {
                    const int koff = (k & 1) * (TY * TX) + ((k >> 1) & 1) * TX
                                   + ((k >> 2) & 1);
                    atomicMax(&sm_out[(cb + koff) * NC + ch], xform(m[k]));
                }
            }
        }
    }
#undef PROC

    // ---- global overflow net (expected empty) ----
    int on = *ovf_n;
    if (on > 0 && tid == 0) {
        if (on > OVF_CAP) on = OVF_CAP;
        for (int e = 0; e < on; ++e) {
            int2 ov = ovf[e];
            int bx = ov.x & (OW - 1);
            int by = (ov.x >> 5) & (OH - 1);
            int rest2 = ov.x >> 10;            // b*OD + bz
            int bb = (rest2 >= OD) ? 1 : 0;
            int bz = rest2 - bb * OD;
            if (bb != b) continue;
            int rz = bz - (tz0 - 1), ry = by - (ty0 - 1), rx = bx - (tx0 - 1);
            if (rz < 0 || rz >= 5 || ry < 0 || ry >= 5 || rx < 0 || rx >= 5) continue;
            int bi = rz - 1, bj = ry - 1, bl = rx - 1;
            int vm = 0xFF;
            if (bi < 0) vm &= 0xAA;  if (bi > TZ - 2) vm &= 0x55;
            if (bj < 0) vm &= 0xCC;  if (bj > TY - 2) vm &= 0x33;
            if (bl < 0) vm &= 0xF0;  if (bl > TX - 2) vm &= 0x0F;
            int fm = ov.y & vm & 0xFF;
            if (fm) slow_apply(sm_out, feat, ov.y, fm,
                               bi * (TY * TX) + bj * TX + bl);
        }
    }
    __syncthreads();

    // ---- epilogue: 64 cells x 8 float4 = 512 stores, one per thread ----
    {
        const int cell = tid >> 3, quad = tid & 7;
        const int i = cell >> 4, jj = (cell >> 2) & 3, l = cell & 3;
        uint4 uv = *(const uint4*)&sm_out[cell * NC + quad * 4];
        float4 o;
        o.x = unxform(uv.x); o.y = unxform(uv.y);
        o.z = unxform(uv.z); o.w = unxform(uv.w);
        out4[(((size_t)(b * OD + tz0 + i) * OH + (ty0 + jj)) * OW
              + (tx0 + l)) * (NC / 4) + quad] = o;
    }
}

// ---------------- launch ----------------

extern "C" void kernel_launch(void* const* d_in, const int* in_sizes, int n_in,
                              void* d_out, int out_size, void* d_ws, size_t ws_size,
                              hipStream_t stream) {
    const float* feat  = (const float*)d_in[0];
    const int*   coors = (const int*)d_in[1];
    const int N = in_sizes[0] / NC;          // 200000
    float4* out4 = (float4*)d_out;           // 1572864 floats

    int*  counts  = (int*)d_ws;                     // NBINS
    int*  ovf_n   = counts + NBINS;                 // 1 (+7 pad)
    int*  records = counts + NBINS + 8;             // NBINS*16
    int2* ovf     = (int2*)(records + (size_t)NBINS * RSTRIDE);

    k_zero<<<(NBINS + 255) / 256, 256, 0, stream>>>(counts, ovf_n);
    k_bin <<<(N + 255) / 256, 256, 0, stream>>>(coors, counts, records,
                                                ovf_n, ovf, N);
    k_tile<<<NTILES, 512, 0, stream>>>(feat, counts, records,
                                       ovf_n, (const int2*)ovf, out4);
}

// Round 17
// 45.056 us; speedup vs baseline: 1.7705x; 1.3058x over previous
//
#include <hip/hip_runtime.h>
#include <cfloat>
#include <cstdint>

// ROUND 17 = ROUND 13 (best: 41.15us, k_tile 19.3us) with ONE change:
// the main loop's 8 predicated LDS atomics per entry are replaced by a
// half-wave-uniform ctz loop -> only actual set bits issue ds_atomic
// (avg 2.6/entry instead of 8). LDS issue count is the measured wall.

// Problem constants (SHAPE=(96,128,128), B=2, C=32, two maxpool(K3,S2,P1) layers)
// Composed pooling: window 7, stride 4, pad 3. Output grid 2 x 24 x 32 x 32 x 32.
#define B_    2
#define OD    24
#define OH    32
#define OW    32
#define NC    32
#define NBINS (B_ * OD * OH * OW)   // 49152
#define RSTRIDE 16                  // record slots per bin
#define OVF_CAP 100000

// tile geometry: 4 x 4 x 4 output cells per workgroup
#define TZ 4
#define TY 4
#define TX 4
#define TCELLS 64
#define NTZ (OD/TZ)                 // 6
#define NTY (OH/TY)                 // 8
#define NTX (OW/TX)                 // 8
#define NTILES (B_*NTZ*NTY*NTX)     // 768 = 3 blocks/CU * 256 CU exactly
#define NBZ (TZ+1)
#define NBY (TY+1)
#define NBX (TX+1)
#define NB  (NBZ*NBY*NBX)           // 125
#define LIST_CAP 1792               // avg entries/tile ~437

// ---------------- monotone float<->uint transform ----------------
__device__ __forceinline__ unsigned xform(float f) {
    unsigned u = __float_as_uint(f);
    return u ^ ((unsigned)((int)u >> 31) | 0x80000000u);
}
__device__ __forceinline__ float unxform(unsigned t) {
    return (t == 0u) ? 0.0f
           : __uint_as_float((t >> 31) ? (t ^ 0x80000000u) : ~t);
}

// rare slow path: apply one record directly to the LDS accumulator
__device__ __forceinline__ void slow_apply(unsigned* sm_out, const float* feat,
                                           int rec, int fm, int cb) {
    unsigned idx = ((unsigned)rec) >> 8;
    for (int c2 = 0; c2 < NC; ++c2) {
        unsigned tvv = xform(feat[idx * NC + c2]);
#pragma unroll
        for (int k = 0; k < 8; ++k) {
            const int koff = ((k & 1) * (TY * TX) + ((k >> 1) & 1) * TX
                           + ((k >> 2) & 1)) * NC;
            if ((fm >> k) & 1) atomicMax(&sm_out[cb * NC + koff + c2], tvv);
        }
    }
}

// ---------------- kernels ----------------

__global__ __launch_bounds__(256) void k_zero(int* __restrict__ counts,
                                              int* __restrict__ ovf_n) {
    int i = blockIdx.x * blockDim.x + threadIdx.x;
    if (i < NBINS) counts[i] = 0;
    if (i == 0) *ovf_n = 0;
}

__global__ __launch_bounds__(256) void k_bin(const int* __restrict__ coors,
                                             int* __restrict__ counts,
                                             int* __restrict__ records,
                                             int* __restrict__ ovf_n,
                                             int2* __restrict__ ovf, int N) {
    int i = blockIdx.x * blockDim.x + threadIdx.x;
    if (i >= N) return;
    int4 cc = reinterpret_cast<const int4*>(coors)[i];   // b, z, y, x
    int bin = (((cc.x * OD + (cc.y >> 2)) * OH + (cc.z >> 2)) * OW + (cc.w >> 2));
    // bit k (k = lz + 2*ly + 4*lx): point qualifies for cell bin+(lz,ly,lx)
    int mask = 0xFF;
    if (!(cc.y & 3)) mask &= 0x55;
    if (!(cc.z & 3)) mask &= 0x33;
    if (!(cc.w & 3)) mask &= 0x0F;
    int rec = (i << 8) | mask;   // mask bit0 always set -> rec != 0
    int pos = atomicAdd(&counts[bin], 1);
    if (pos < RSTRIDE) {
        records[bin * RSTRIDE + pos] = rec;
    } else {
        int o = atomicAdd(ovf_n, 1);
        if (o < OVF_CAP) ovf[o] = make_int2(bin, rec);
    }
}

__global__ __launch_bounds__(512) void k_tile(const float* __restrict__ feat,
                                              const int* __restrict__ counts,
                                              const int* __restrict__ records,
                                              const int* __restrict__ ovf_n,
                                              const int2* __restrict__ ovf,
                                              float4* __restrict__ out4) {
    __shared__ unsigned sm_out[TCELLS * NC];   // 8 KB
    __shared__ int2 list[LIST_CAP];            // 14 KB
    __shared__ int sm_cursor;

    // XCD-aware swizzle (768 % 8 == 0 -> bijective)
    const int t   = (blockIdx.x & 7) * (NTILES / 8) + (blockIdx.x >> 3);
    const int tid = threadIdx.x;
    const int tx_ = t & (NTX - 1);
    const int ty_ = (t >> 3) & (NTY - 1);
    const int rest = t >> 6;                   // b*NTZ + tz, 0..11
    const int b   = (rest >= NTZ) ? 1 : 0;
    const int tz_ = rest - b * NTZ;
    const int tz0 = tz_ * TZ, ty0 = ty_ * TY, tx0 = tx_ * TX;

    if (tid == 0) sm_cursor = 0;
    for (int v = tid; v < TCELLS * NC; v += 512) sm_out[v] = 0u;
    __syncthreads();

    // ---- build compact entry list: FOUR threads per neighborhood bin ----
    if (tid < 4 * NB) {                        // 500 threads
        int bn  = tid >> 2;                    // bin 0..124
        int sl  = tid & 3;                     // record quad 0..3
        int rz  = bn / (NBY * NBX);
        int rem = bn - rz * (NBY * NBX);
        int ry  = rem / NBX;
        int rx  = rem - ry * NBX;
        int bz = tz0 - 1 + rz, by = ty0 - 1 + ry, bx = tx0 - 1 + rx;
        if ((bz | by | bx) >= 0) {             // upper side in-grid by tiling
            int bin = ((b * OD + bz) * OH + by) * OW + bx;
            int cnt = counts[bin]; if (cnt > RSTRIDE) cnt = RSTRIDE;
            int4 q = *(const int4*)(records + bin * RSTRIDE + sl * 4);
            int bi = rz - 1, bj = ry - 1, bl = rx - 1;
            int vm = 0xFF;                     // tile-validity mask per k
            if (bi < 0) vm &= 0xAA;  if (bi > TZ - 2) vm &= 0x55;
            if (bj < 0) vm &= 0xCC;  if (bj > TY - 2) vm &= 0x33;
            if (bl < 0) vm &= 0xF0;  if (bl > TX - 2) vm &= 0x0F;
            int cb = bi * (TY * TX) + bj * TX + bl;
            int rs0 = sl << 2;
            int f0 = (rs0 + 0 < cnt) ? (q.x & vm & 0xFF) : 0;
            int f1 = (rs0 + 1 < cnt) ? (q.y & vm & 0xFF) : 0;
            int f2 = (rs0 + 2 < cnt) ? (q.z & vm & 0xFF) : 0;
            int f3 = (rs0 + 3 < cnt) ? (q.w & vm & 0xFF) : 0;
            int nk = (f0 != 0) + (f1 != 0) + (f2 != 0) + (f3 != 0);
            if (nk) {
                int pos = atomicAdd(&sm_cursor, nk);
                if (f0) { if (pos < LIST_CAP) list[pos] = make_int2((q.x & ~0xFF) | f0, cb);
                          else slow_apply(sm_out, feat, q.x, f0, cb); ++pos; }
                if (f1) { if (pos < LIST_CAP) list[pos] = make_int2((q.y & ~0xFF) | f1, cb);
                          else slow_apply(sm_out, feat, q.y, f1, cb); ++pos; }
                if (f2) { if (pos < LIST_CAP) list[pos] = make_int2((q.z & ~0xFF) | f2, cb);
                          else slow_apply(sm_out, feat, q.z, f2, cb); ++pos; }
                if (f3) { if (pos < LIST_CAP) list[pos] = make_int2((q.w & ~0xFF) | f3, cb);
                          else slow_apply(sm_out, feat, q.w, f3, cb); ++pos; }
            }
        }
    }

    // ---- global overflow net (expected empty) ----
    int on = *ovf_n;
    if (on > 0 && tid == 0) {
        if (on > OVF_CAP) on = OVF_CAP;
        for (int e = 0; e < on; ++e) {
            int2 ov = ovf[e];
            int bx = ov.x & (OW - 1);
            int by = (ov.x >> 5) & (OH - 1);
            int rest2 = ov.x >> 10;            // b*OD + bz
            int bb = (rest2 >= OD) ? 1 : 0;
            int bz = rest2 - bb * OD;
            if (bb != b) continue;
            int rz = bz - (tz0 - 1), ry = by - (ty0 - 1), rx = bx - (tx0 - 1);
            if (rz < 0 || rz >= NBZ || ry < 0 || ry >= NBY || rx < 0 || rx >= NBX) continue;
            int bi = rz - 1, bj = ry - 1, bl = rx - 1;
            int vm = 0xFF;
            if (bi < 0) vm &= 0xAA;  if (bi > TZ - 2) vm &= 0x55;
            if (bj < 0) vm &= 0xCC;  if (bj > TY - 2) vm &= 0x33;
            if (bl < 0) vm &= 0xF0;  if (bl > TX - 2) vm &= 0x0F;
            int fm = ov.y & vm & 0xFF;
            if (fm) {
                int pos = atomicAdd(&sm_cursor, 1);
                if (pos < LIST_CAP)
                    list[pos] = make_int2((ov.y & ~0xFF) | fm,
                                          bi * (TY * TX) + bj * TX + bl);
            }
        }
    }
    __syncthreads();
    int total = sm_cursor; if (total > LIST_CAP) total = LIST_CAP;

    // ---- main loop: 16 slots x 8-deep ILP; DENSE ctz-loop atomics ----
    // fm is uniform across each half-wave (all 32 channels share the entry),
    // so the while loop has uniform trips per half-wave: every issued
    // ds_atomic carries a full half-wave (or full wave) of useful lanes.
    const int s = tid >> 5;
    const int c = tid & 31;

    for (int j0 = s; j0 < total; j0 += 128) {
        int2 e[8];
        unsigned tv[8];
#pragma unroll
        for (int u = 0; u < 8; ++u) {
            int j = j0 + 16 * u;
            e[u] = (j < total) ? list[j] : make_int2(0, 0);   // fm=0 -> no-op
        }
#pragma unroll
        for (int u = 0; u < 8; ++u)
            tv[u] = xform(feat[(((unsigned)e[u].x) >> 8) * NC + c]);
#pragma unroll
        for (int u = 0; u < 8; ++u) {
            int fm = e[u].x & 0xFF;            // half-wave-uniform
            const int base = e[u].y;
            while (fm) {
                int k = __ffs(fm) - 1;
                fm &= fm - 1;
                int koff = (k & 1) * (TY * TX) + ((k >> 1) & 1) * TX
                         + ((k >> 2) & 1);
                atomicMax(&sm_out[(base + koff) * NC + c], tv[u]);
            }
        }
    }
    __syncthreads();

    // ---- epilogue: 64 cells x 8 float4 = 512 stores, one per thread ----
    {
        const int cell = tid >> 3, quad = tid & 7;
        const int i = cell >> 4, jj = (cell >> 2) & 3, l = cell & 3;
        uint4 uv = *(const uint4*)&sm_out[cell * NC + quad * 4];
        float4 o;
        o.x = unxform(uv.x); o.y = unxform(uv.y);
        o.z = unxform(uv.z); o.w = unxform(uv.w);
        out4[(((size_t)(b * OD + tz0 + i) * OH + (ty0 + jj)) * OW
              + (tx0 + l)) * (NC / 4) + quad] = o;
    }
}

// ---------------- launch ----------------

extern "C" void kernel_launch(void* const* d_in, const int* in_sizes, int n_in,
                              void* d_out, int out_size, void* d_ws, size_t ws_size,
                              hipStream_t stream) {
    const float* feat  = (const float*)d_in[0];
    const int*   coors = (const int*)d_in[1];
    const int N = in_sizes[0] / NC;          // 200000
    float4* out4 = (float4*)d_out;           // 1572864 floats

    int*  counts  = (int*)d_ws;                     // NBINS
    int*  ovf_n   = counts + NBINS;                 // 1 (+7 pad)
    int*  records = counts + NBINS + 8;             // NBINS*16
    int2* ovf     = (int2*)(records + (size_t)NBINS * RSTRIDE);

    k_zero<<<(NBINS + 255) / 256, 256, 0, stream>>>(counts, ovf_n);
    k_bin <<<(N + 255) / 256, 256, 0, stream>>>(coors, counts, records,
                                                ovf_n, ovf, N);
    k_tile<<<NTILES, 512, 0, stream>>>(feat, counts, records,
                                       ovf_n, (const int2*)ovf, out4);
}

// Round 18
// 40.524 us; speedup vs baseline: 1.9685x; 1.1118x over previous
//
#include <hip/hip_runtime.h>
#include <cfloat>
#include <cstdint>

// ROUND 18 = ROUND 13 (best: 41.15us, k_tile 19.3us) with ONE change:
// build-phase list reservation is wave-aggregated (shfl prefix-sum + one
// atomicAdd per wave) instead of ~340 serialized same-address LDS RMWs.

// Problem constants (SHAPE=(96,128,128), B=2, C=32, two maxpool(K3,S2,P1) layers)
// Composed pooling: window 7, stride 4, pad 3. Output grid 2 x 24 x 32 x 32 x 32.
#define B_    2
#define OD    24
#define OH    32
#define OW    32
#define NC    32
#define NBINS (B_ * OD * OH * OW)   // 49152
#define RSTRIDE 16                  // record slots per bin
#define OVF_CAP 100000

// tile geometry: 4 x 4 x 4 output cells per workgroup
#define TZ 4
#define TY 4
#define TX 4
#define TCELLS 64
#define NTZ (OD/TZ)                 // 6
#define NTY (OH/TY)                 // 8
#define NTX (OW/TX)                 // 8
#define NTILES (B_*NTZ*NTY*NTX)     // 768 = 3 blocks/CU * 256 CU exactly
#define NBZ (TZ+1)
#define NBY (TY+1)
#define NBX (TX+1)
#define NB  (NBZ*NBY*NBX)           // 125
#define LIST_CAP 1792               // avg entries/tile ~437

// ---------------- monotone float<->uint transform ----------------
__device__ __forceinline__ unsigned xform(float f) {
    unsigned u = __float_as_uint(f);
    return u ^ ((unsigned)((int)u >> 31) | 0x80000000u);
}
__device__ __forceinline__ float unxform(unsigned t) {
    return (t == 0u) ? 0.0f
           : __uint_as_float((t >> 31) ? (t ^ 0x80000000u) : ~t);
}

// rare slow path: apply one record directly to the LDS accumulator
__device__ __forceinline__ void slow_apply(unsigned* sm_out, const float* feat,
                                           int rec, int fm, int cb) {
    unsigned idx = ((unsigned)rec) >> 8;
    for (int c2 = 0; c2 < NC; ++c2) {
        unsigned tvv = xform(feat[idx * NC + c2]);
#pragma unroll
        for (int k = 0; k < 8; ++k) {
            const int koff = ((k & 1) * (TY * TX) + ((k >> 1) & 1) * TX
                           + ((k >> 2) & 1)) * NC;
            if ((fm >> k) & 1) atomicMax(&sm_out[cb * NC + koff + c2], tvv);
        }
    }
}

// ---------------- kernels ----------------

__global__ __launch_bounds__(256) void k_zero(int* __restrict__ counts,
                                              int* __restrict__ ovf_n) {
    int i = blockIdx.x * blockDim.x + threadIdx.x;
    if (i < NBINS) counts[i] = 0;
    if (i == 0) *ovf_n = 0;
}

__global__ __launch_bounds__(256) void k_bin(const int* __restrict__ coors,
                                             int* __restrict__ counts,
                                             int* __restrict__ records,
                                             int* __restrict__ ovf_n,
                                             int2* __restrict__ ovf, int N) {
    int i = blockIdx.x * blockDim.x + threadIdx.x;
    if (i >= N) return;
    int4 cc = reinterpret_cast<const int4*>(coors)[i];   // b, z, y, x
    int bin = (((cc.x * OD + (cc.y >> 2)) * OH + (cc.z >> 2)) * OW + (cc.w >> 2));
    // bit k (k = lz + 2*ly + 4*lx): point qualifies for cell bin+(lz,ly,lx)
    int mask = 0xFF;
    if (!(cc.y & 3)) mask &= 0x55;
    if (!(cc.z & 3)) mask &= 0x33;
    if (!(cc.w & 3)) mask &= 0x0F;
    int rec = (i << 8) | mask;   // mask bit0 always set -> rec != 0
    int pos = atomicAdd(&counts[bin], 1);
    if (pos < RSTRIDE) {
        records[bin * RSTRIDE + pos] = rec;
    } else {
        int o = atomicAdd(ovf_n, 1);
        if (o < OVF_CAP) ovf[o] = make_int2(bin, rec);
    }
}

__global__ __launch_bounds__(512) void k_tile(const float* __restrict__ feat,
                                              const int* __restrict__ counts,
                                              const int* __restrict__ records,
                                              const int* __restrict__ ovf_n,
                                              const int2* __restrict__ ovf,
                                              float4* __restrict__ out4) {
    __shared__ unsigned sm_out[TCELLS * NC];   // 8 KB
    __shared__ int2 list[LIST_CAP];            // 14 KB
    __shared__ int sm_cursor;

    // XCD-aware swizzle (768 % 8 == 0 -> bijective)
    const int t   = (blockIdx.x & 7) * (NTILES / 8) + (blockIdx.x >> 3);
    const int tid = threadIdx.x;
    const int tx_ = t & (NTX - 1);
    const int ty_ = (t >> 3) & (NTY - 1);
    const int rest = t >> 6;                   // b*NTZ + tz, 0..11
    const int b   = (rest >= NTZ) ? 1 : 0;
    const int tz_ = rest - b * NTZ;
    const int tz0 = tz_ * TZ, ty0 = ty_ * TY, tx0 = tx_ * TX;

    if (tid == 0) sm_cursor = 0;
    for (int v = tid; v < TCELLS * NC; v += 512) sm_out[v] = 0u;
    __syncthreads();

    // ---- build compact entry list: FOUR threads per neighborhood bin ----
    // Reservation is wave-aggregated: shfl prefix-sum of nk, one atomicAdd
    // per wave (lane 63), base broadcast. All threads run the scan.
    int f0 = 0, f1 = 0, f2 = 0, f3 = 0, cb = 0, nk = 0;
    int4 q = make_int4(0, 0, 0, 0);
    if (tid < 4 * NB) {                        // 500 threads
        int bn  = tid >> 2;                    // bin 0..124
        int sl  = tid & 3;                     // record quad 0..3
        int rz  = bn / (NBY * NBX);
        int rem = bn - rz * (NBY * NBX);
        int ry  = rem / NBX;
        int rx  = rem - ry * NBX;
        int bz = tz0 - 1 + rz, by = ty0 - 1 + ry, bx = tx0 - 1 + rx;
        if ((bz | by | bx) >= 0) {             // upper side in-grid by tiling
            int bin = ((b * OD + bz) * OH + by) * OW + bx;
            int cnt = counts[bin]; if (cnt > RSTRIDE) cnt = RSTRIDE;
            q = *(const int4*)(records + bin * RSTRIDE + sl * 4);
            int bi = rz - 1, bj = ry - 1, bl = rx - 1;
            int vm = 0xFF;                     // tile-validity mask per k
            if (bi < 0) vm &= 0xAA;  if (bi > TZ - 2) vm &= 0x55;
            if (bj < 0) vm &= 0xCC;  if (bj > TY - 2) vm &= 0x33;
            if (bl < 0) vm &= 0xF0;  if (bl > TX - 2) vm &= 0x0F;
            cb = bi * (TY * TX) + bj * TX + bl;
            int rs0 = sl << 2;
            f0 = (rs0 + 0 < cnt) ? (q.x & vm & 0xFF) : 0;
            f1 = (rs0 + 1 < cnt) ? (q.y & vm & 0xFF) : 0;
            f2 = (rs0 + 2 < cnt) ? (q.z & vm & 0xFF) : 0;
            f3 = (rs0 + 3 < cnt) ? (q.w & vm & 0xFF) : 0;
            nk = (f0 != 0) + (f1 != 0) + (f2 != 0) + (f3 != 0);
        }
    }
    {
        const int lane = tid & 63;
        int inc = nk;                          // inclusive prefix within wave
#pragma unroll
        for (int d = 1; d < 64; d <<= 1) {
            int v = __shfl_up(inc, d, 64);
            if (lane >= d) inc += v;
        }
        int wtot = __shfl(inc, 63, 64);        // wave total
        int wbase = 0;
        if (wtot > 0) {
            if (lane == 63) wbase = atomicAdd(&sm_cursor, wtot);
            wbase = __shfl(wbase, 63, 64);
        }
        int pos = wbase + inc - nk;            // exclusive prefix + base
        if (nk) {
            if (f0) { if (pos < LIST_CAP) list[pos] = make_int2((q.x & ~0xFF) | f0, cb);
                      else slow_apply(sm_out, feat, q.x, f0, cb); ++pos; }
            if (f1) { if (pos < LIST_CAP) list[pos] = make_int2((q.y & ~0xFF) | f1, cb);
                      else slow_apply(sm_out, feat, q.y, f1, cb); ++pos; }
            if (f2) { if (pos < LIST_CAP) list[pos] = make_int2((q.z & ~0xFF) | f2, cb);
                      else slow_apply(sm_out, feat, q.z, f2, cb); ++pos; }
            if (f3) { if (pos < LIST_CAP) list[pos] = make_int2((q.w & ~0xFF) | f3, cb);
                      else slow_apply(sm_out, feat, q.w, f3, cb); ++pos; }
        }
    }

    // ---- global overflow net (expected empty) ----
    int on = *ovf_n;
    if (on > 0 && tid == 0) {
        if (on > OVF_CAP) on = OVF_CAP;
        for (int e = 0; e < on; ++e) {
            int2 ov = ovf[e];
            int bx = ov.x & (OW - 1);
            int by = (ov.x >> 5) & (OH - 1);
            int rest2 = ov.x >> 10;            // b*OD + bz
            int bb = (rest2 >= OD) ? 1 : 0;
            int bz = rest2 - bb * OD;
            if (bb != b) continue;
            int rz = bz - (tz0 - 1), ry = by - (ty0 - 1), rx = bx - (tx0 - 1);
            if (rz < 0 || rz >= NBZ || ry < 0 || ry >= NBY || rx < 0 || rx >= NBX) continue;
            int bi = rz - 1, bj = ry - 1, bl = rx - 1;
            int vm = 0xFF;
            if (bi < 0) vm &= 0xAA;  if (bi > TZ - 2) vm &= 0x55;
            if (bj < 0) vm &= 0xCC;  if (bj > TY - 2) vm &= 0x33;
            if (bl < 0) vm &= 0xF0;  if (bl > TX - 2) vm &= 0x0F;
            int fm = ov.y & vm & 0xFF;
            if (fm) {
                int pos = atomicAdd(&sm_cursor, 1);
                if (pos < LIST_CAP)
                    list[pos] = make_int2((ov.y & ~0xFF) | fm,
                                          bi * (TY * TX) + bj * TX + bl);
            }
        }
    }
    __syncthreads();
    int total = sm_cursor; if (total > LIST_CAP) total = LIST_CAP;

    // ---- main loop: 16 slots x 8-deep ILP = 128 entries per round ----
    const int s = tid >> 5;
    const int c = tid & 31;

    for (int j0 = s; j0 < total; j0 += 128) {
        int2 e[8];
        unsigned tv[8];
#pragma unroll
        for (int u = 0; u < 8; ++u) {
            int j = j0 + 16 * u;
            e[u] = (j < total) ? list[j] : make_int2(0, 0);   // fm=0 -> no-op
        }
#pragma unroll
        for (int u = 0; u < 8; ++u)
            tv[u] = xform(feat[(((unsigned)e[u].x) >> 8) * NC + c]);
#pragma unroll
        for (int u = 0; u < 8; ++u) {
#pragma unroll
            for (int k = 0; k < 8; ++k) {
                const int koff = ((k & 1) * (TY * TX) + ((k >> 1) & 1) * TX
                               + ((k >> 2) & 1)) * NC + c;
                if ((e[u].x >> k) & 1) atomicMax(&sm_out[e[u].y * NC + koff], tv[u]);
            }
        }
    }
    __syncthreads();

    // ---- epilogue: 64 cells x 8 float4 = 512 stores, one per thread ----
    {
        const int cell = tid >> 3, quad = tid & 7;
        const int i = cell >> 4, jj = (cell >> 2) & 3, l = cell & 3;
        uint4 uv = *(const uint4*)&sm_out[cell * NC + quad * 4];
        float4 o;
        o.x = unxform(uv.x); o.y = unxform(uv.y);
        o.z = unxform(uv.z); o.w = unxform(uv.w);
        out4[(((size_t)(b * OD + tz0 + i) * OH + (ty0 + jj)) * OW
              + (tx0 + l)) * (NC / 4) + quad] = o;
    }
}

// ---------------- launch ----------------

extern "C" void kernel_launch(void* const* d_in, const int* in_sizes, int n_in,
                              void* d_out, int out_size, void* d_ws, size_t ws_size,
                              hipStream_t stream) {
    const float* feat  = (const float*)d_in[0];
    const int*   coors = (const int*)d_in[1];
    const int N = in_sizes[0] / NC;          // 200000
    float4* out4 = (float4*)d_out;           // 1572864 floats

    int*  counts  = (int*)d_ws;                     // NBINS
    int*  ovf_n   = counts + NBINS;                 // 1 (+7 pad)
    int*  records = counts + NBINS + 8;             // NBINS*16
    int2* ovf     = (int2*)(records + (size_t)NBINS * RSTRIDE);

    k_zero<<<(NBINS + 255) / 256, 256, 0, stream>>>(counts, ovf_n);
    k_bin <<<(N + 255) / 256, 256, 0, stream>>>(coors, counts, records,
                                                ovf_n, ovf, N);
    k_tile<<<NTILES, 512, 0, stream>>>(feat, counts, records,
                                       ovf_n, (const int2*)ovf, out4);
}